// Round 1
// baseline (674.577 us; speedup 1.0000x reference)
//
#include <hip/hip_runtime.h>
#include <math.h>

#define EPSF 1e-5f

constexpr int SEQ = 512;
constexpr int DIM = 512;
constexpr int BSZ = 2;
constexpr int NH  = 8;
constexpr int HD  = 64;

// y = x @ W.T + bias ; x:(M,K) W:(N,K) y:(M,N). One block per row m.
__global__ __launch_bounds__(256) void linear_kernel(
    const float* __restrict__ x, const float* __restrict__ W,
    const float* __restrict__ bias, float* __restrict__ y,
    int M, int N, int K) {
  __shared__ float xs[DIM];
  int m = blockIdx.x;
  for (int k = threadIdx.x; k < K; k += 256) xs[k] = x[(size_t)m * K + k];
  __syncthreads();
  for (int n = threadIdx.x; n < N; n += 256) {
    const float4* wr = reinterpret_cast<const float4*>(W + (size_t)n * K);
    float acc = 0.f;
#pragma unroll 8
    for (int k4 = 0; k4 < K / 4; ++k4) {
      float4 w = wr[k4];
      acc = fmaf(xs[4 * k4 + 0], w.x, acc);
      acc = fmaf(xs[4 * k4 + 1], w.y, acc);
      acc = fmaf(xs[4 * k4 + 2], w.z, acc);
      acc = fmaf(xs[4 * k4 + 3], w.w, acc);
    }
    y[(size_t)m * N + n] = acc + bias[n];
  }
}

// In-place exp_map_zero + project per contiguous 64-float head vector.
// Combined multiplier: mu = min(tanh(r), 0.999)/r, r = max(||v||, EPS).
// Resulting squared norm: min(tanh(r),0.999)^2 -> written to n2[vec].
__global__ __launch_bounds__(256) void expmap_kernel(
    float* __restrict__ t, float* __restrict__ n2, int nvec) {
  int vec = blockIdx.x * 4 + (threadIdx.x >> 6);
  int lane = threadIdx.x & 63;
  if (vec >= nvec) return;
  float val = t[(size_t)vec * HD + lane];
  float ss = val * val;
#pragma unroll
  for (int m = 1; m < 64; m <<= 1) ss += __shfl_xor(ss, m);
  float r = fmaxf(sqrtf(ss), EPSF);
  float tn = fminf(tanhf(r), 0.999f);
  float mu = tn / r;
  t[(size_t)vec * HD + lane] = val * mu;
  if (lane == 0) n2[vec] = tn * tn;
}

// One block (256 thr) per (b, h, query). Computes hyperbolic-distance logits
// over all 512 keys, softmax, then attn @ V for the 64-dim head output.
__global__ __launch_bounds__(256) void attn_kernel(
    const float* __restrict__ qh, const float* __restrict__ kh,
    const float* __restrict__ v, const float* __restrict__ qn2,
    const float* __restrict__ kn2, float* __restrict__ ctx) {
  int qi = blockIdx.x, h = blockIdx.y, b = blockIdx.z;
  int t = threadIdx.x;
  __shared__ float qs[HD];
  __shared__ float wbuf[SEQ];
  __shared__ float red[256];
  __shared__ float partial[4][HD];

  const float* qrow = qh + ((size_t)(b * SEQ + qi) * DIM + h * HD);
  if (t < HD) qs[t] = qrow[t];
  __syncthreads();

  float qn = qn2[(b * SEQ + qi) * NH + h];
  float B = 1.f - qn;
  float lg[2];
  float lmax = -1e30f;
#pragma unroll
  for (int rep = 0; rep < 2; ++rep) {
    int j = t + rep * 256;
    const float4* krow = reinterpret_cast<const float4*>(
        kh + ((size_t)(b * SEQ + j) * DIM + h * HD));
    float dot = 0.f;
#pragma unroll
    for (int d4 = 0; d4 < HD / 4; ++d4) {
      float4 kv = krow[d4];
      dot = fmaf(qs[4 * d4 + 0], kv.x, dot);
      dot = fmaf(qs[4 * d4 + 1], kv.y, dot);
      dot = fmaf(qs[4 * d4 + 2], kv.z, dot);
      dot = fmaf(qs[4 * d4 + 3], kv.w, dot);
    }
    float kn = kn2[(b * SEQ + j) * NH + h];
    float A = 1.f - 2.f * dot + kn;
    float den = 1.f - 2.f * dot + qn * kn;
    float num2 = fmaxf(A * A * qn - 2.f * A * B * dot + B * B * kn, 0.f);
    float on = sqrtf(num2) / fmaxf(den, EPSF);
    float n1 = fminf(on, 0.999f);
    float dist = logf((1.f + n1) / (1.f - n1));  // 2*atanh(n1)
    float logit = fmaxf(fminf(-dist * 0.125f, 0.f), -50.f);
    lg[rep] = logit;
    lmax = fmaxf(lmax, logit);
  }
  // block max-reduce
  red[t] = lmax;
  __syncthreads();
  for (int s = 128; s > 0; s >>= 1) {
    if (t < s) red[t] = fmaxf(red[t], red[t + s]);
    __syncthreads();
  }
  float mx = red[0];
  __syncthreads();
  // exp + sum-reduce
  float lsum = 0.f;
#pragma unroll
  for (int rep = 0; rep < 2; ++rep) {
    float w = expf(lg[rep] - mx);
    wbuf[t + rep * 256] = w;
    lsum += w;
  }
  red[t] = lsum;
  __syncthreads();
  for (int s = 128; s > 0; s >>= 1) {
    if (t < s) red[t] += red[t + s];
    __syncthreads();
  }
  float inv = 1.f / red[0];
  __syncthreads();

  // output: thread t -> dim d = t&63, key-chunk = t>>6 (128 keys each)
  int d = t & 63;
  int chunk = t >> 6;
  float acc = 0.f;
  const float* vbase = v + ((size_t)b * SEQ * DIM + h * HD + d);
  for (int j = chunk * 128; j < (chunk + 1) * 128; ++j) {
    acc = fmaf(wbuf[j], vbase[(size_t)j * DIM], acc);
  }
  partial[chunk][d] = acc;
  __syncthreads();
  if (t < HD) {
    float o = (partial[0][t] + partial[1][t] + partial[2][t] + partial[3][t]) * inv;
    ctx[(size_t)(b * SEQ + qi) * DIM + h * HD + t] = o;
  }
}

extern "C" void kernel_launch(void* const* d_in, const int* in_sizes, int n_in,
                              void* d_out, int out_size, void* d_ws, size_t ws_size,
                              hipStream_t stream) {
  const float* x  = (const float*)d_in[0];
  const float* Wq = (const float*)d_in[1];
  const float* bq = (const float*)d_in[2];
  const float* Wk = (const float*)d_in[3];
  const float* bk = (const float*)d_in[4];
  const float* Wv = (const float*)d_in[5];
  const float* bv = (const float*)d_in[6];
  const float* Wo = (const float*)d_in[7];
  const float* bo = (const float*)d_in[8];

  float* ws  = (float*)d_ws;
  const int M = BSZ * SEQ;            // 1024
  const size_t TOK = (size_t)M * DIM; // 524288
  float* q   = ws;
  float* k   = q + TOK;
  float* v   = k + TOK;
  float* ctx = v + TOK;
  float* qn2 = ctx + TOK;
  float* kn2 = qn2 + (size_t)M * NH;

  linear_kernel<<<M, 256, 0, stream>>>(x, Wq, bq, q, M, DIM, DIM);
  linear_kernel<<<M, 256, 0, stream>>>(x, Wk, bk, k, M, DIM, DIM);
  linear_kernel<<<M, 256, 0, stream>>>(x, Wv, bv, v, M, DIM, DIM);

  int nvec = M * NH;  // 8192 head-vectors each
  expmap_kernel<<<(nvec + 3) / 4, 256, 0, stream>>>(q, qn2, nvec);
  expmap_kernel<<<(nvec + 3) / 4, 256, 0, stream>>>(k, kn2, nvec);

  dim3 g(SEQ, NH, BSZ);
  attn_kernel<<<g, 256, 0, stream>>>(q, k, v, qn2, kn2, ctx);

  linear_kernel<<<M, 256, 0, stream>>>(ctx, Wo, bo, (float*)d_out, M, DIM, DIM);
}

// Round 2
// 128.123 us; speedup vs baseline: 5.2651x; 5.2651x over previous
//
#include <hip/hip_runtime.h>
#include <math.h>

#define EPSF 1e-5f

constexpr int SEQ = 512;
constexpr int DIM = 512;
constexpr int BSZ = 2;
constexpr int NH  = 8;
constexpr int HD  = 64;

// ---- tiled GEMM: y = x @ W.T + b. 64x64 tile, 256 thr, 4x4 per thread.
// blockIdx.z selects among 3 weight/bias/out sets (for fused QKV).
__global__ __launch_bounds__(256) void gemm3_kernel(
    const float* __restrict__ x,
    const float* __restrict__ W0, const float* __restrict__ W1, const float* __restrict__ W2,
    const float* __restrict__ b0, const float* __restrict__ b1, const float* __restrict__ b2,
    float* __restrict__ y0, float* __restrict__ y1, float* __restrict__ y2) {
  const float* W    = blockIdx.z == 0 ? W0 : (blockIdx.z == 1 ? W1 : W2);
  const float* bias = blockIdx.z == 0 ? b0 : (blockIdx.z == 1 ? b1 : b2);
  float*       y    = blockIdx.z == 0 ? y0 : (blockIdx.z == 1 ? y1 : y2);

  __shared__ float xs[16][68];
  __shared__ float ws[16][68];
  int t = threadIdx.x;
  int m0 = blockIdx.x * 64, n0 = blockIdx.y * 64;
  int tn = t & 15, tm = t >> 4;
  int lr = t >> 2, lc = t & 3;

  const float* xp = x + (size_t)(m0 + lr) * DIM + lc * 4;
  const float* wp = W + (size_t)(n0 + lr) * DIM + lc * 4;
  float4 xv = *(const float4*)xp;
  float4 wv = *(const float4*)wp;
  float acc[4][4] = {};

  for (int k0 = 16; k0 <= DIM; k0 += 16) {
    __syncthreads();
    xs[lc * 4 + 0][lr] = xv.x; xs[lc * 4 + 1][lr] = xv.y;
    xs[lc * 4 + 2][lr] = xv.z; xs[lc * 4 + 3][lr] = xv.w;
    ws[lc * 4 + 0][lr] = wv.x; ws[lc * 4 + 1][lr] = wv.y;
    ws[lc * 4 + 2][lr] = wv.z; ws[lc * 4 + 3][lr] = wv.w;
    __syncthreads();
    if (k0 < DIM) {  // register prefetch of next tile overlaps compute
      xv = *(const float4*)(xp + k0);
      wv = *(const float4*)(wp + k0);
    }
#pragma unroll
    for (int kk = 0; kk < 16; ++kk) {
      float4 a = *(float4*)&xs[kk][tm * 4];
      float4 bb = *(float4*)&ws[kk][tn * 4];
      float av[4] = {a.x, a.y, a.z, a.w};
      float bv[4] = {bb.x, bb.y, bb.z, bb.w};
#pragma unroll
      for (int i = 0; i < 4; ++i)
#pragma unroll
        for (int j = 0; j < 4; ++j)
          acc[i][j] = fmaf(av[i], bv[j], acc[i][j]);
    }
  }
  float4 b4 = *(const float4*)(bias + n0 + tn * 4);
#pragma unroll
  for (int i = 0; i < 4; ++i) {
    float4 o = make_float4(acc[i][0] + b4.x, acc[i][1] + b4.y,
                           acc[i][2] + b4.z, acc[i][3] + b4.w);
    *(float4*)(y + (size_t)(m0 + tm * 4 + i) * DIM + n0 + tn * 4) = o;
  }
}

// In-place exp_map_zero + project per 64-float head vector.
__global__ __launch_bounds__(256) void expmap_kernel(
    float* __restrict__ t, float* __restrict__ n2, int nvec) {
  int vec = blockIdx.x * 4 + (threadIdx.x >> 6);
  int lane = threadIdx.x & 63;
  if (vec >= nvec) return;
  float val = t[(size_t)vec * HD + lane];
  float ss = val * val;
#pragma unroll
  for (int m = 1; m < 64; m <<= 1) ss += __shfl_xor(ss, m);
  float r = fmaxf(sqrtf(ss), EPSF);
  float tn = fminf(tanhf(r), 0.999f);
  float mu = tn / r;
  t[(size_t)vec * HD + lane] = val * mu;
  if (lane == 0) n2[vec] = tn * tn;
}

// One block per (b, h, 16-query tile). Q in registers, K chunked in LDS,
// exp-weights in LDS (no max pass needed: logits in [-0.95, 0]).
__global__ __launch_bounds__(256) void attn_kernel(
    const float* __restrict__ qh, const float* __restrict__ kh,
    const float* __restrict__ v, const float* __restrict__ qn2,
    const float* __restrict__ kn2, float* __restrict__ ctx) {
  int b = blockIdx.z, h = blockIdx.y, q0 = blockIdx.x * 16;
  int t = threadIdx.x;
  __shared__ float ks[64][68];
  __shared__ float wls[16][524];
  __shared__ float red[256];
  __shared__ float qn2s[16];
  __shared__ float kn2s[64];
  __shared__ float invs[16];

  int q = t & 15, kc = t >> 4;
  const float4* qrow = (const float4*)(qh + (size_t)(b * SEQ + q0 + q) * DIM + h * HD);
  float4 qv[16];
#pragma unroll
  for (int i = 0; i < 16; ++i) qv[i] = qrow[i];
  if (t < 16) qn2s[t] = qn2[(size_t)(b * SEQ + q0 + t) * NH + h];
  __syncthreads();
  float qn = qn2s[q];
  float Bq = 1.f - qn;
  float wsum = 0.f;

  int lr = t >> 4, lcq = t & 15;
  for (int c = 0; c < 8; ++c) {
    __syncthreads();
#pragma unroll
    for (int rr = 0; rr < 4; ++rr) {
      int row = rr * 16 + lr;
      float4 kv = ((const float4*)(kh + (size_t)(b * SEQ + c * 64 + row) * DIM + h * HD))[lcq];
      *(float4*)&ks[row][lcq * 4] = kv;
    }
    if (t < 64) kn2s[t] = kn2[(size_t)(b * SEQ + c * 64 + t) * NH + h];
    __syncthreads();
    float wv4[4];
#pragma unroll
    for (int j = 0; j < 4; ++j) {
      int key = kc * 4 + j;
      float dot = 0.f;
#pragma unroll
      for (int d4 = 0; d4 < 16; ++d4) {
        float4 kv = *(float4*)&ks[key][d4 * 4];
        dot = fmaf(qv[d4].x, kv.x, dot);
        dot = fmaf(qv[d4].y, kv.y, dot);
        dot = fmaf(qv[d4].z, kv.z, dot);
        dot = fmaf(qv[d4].w, kv.w, dot);
      }
      float kn = kn2s[key];
      float A = 1.f - 2.f * dot + kn;
      float den = fmaxf(1.f - 2.f * dot + qn * kn, EPSF);
      float num2 = fmaxf(A * A * qn - 2.f * A * Bq * dot + Bq * Bq * kn, 0.f);
      float n1 = fminf(__fsqrt_rn(num2) / den, 0.999f);
      float dist = __logf((1.f + n1) / (1.f - n1));   // 2*atanh(n1)
      float logit = fminf(fmaxf(-dist * 0.125f, -50.f), 0.f);
      float w = __expf(logit);
      wv4[j] = w;
      wsum += w;
    }
    *(float4*)&wls[q][c * 64 + kc * 4] = make_float4(wv4[0], wv4[1], wv4[2], wv4[3]);
  }
  // per-q sum reduce over kc (red layout: [kc][q], t = kc*16+q)
  red[t] = wsum;
  __syncthreads();
  if (t < 128) red[t] += red[t + 128];
  __syncthreads();
  if (t < 64) red[t] += red[t + 64];
  __syncthreads();
  if (t < 32) red[t] += red[t + 32];
  __syncthreads();
  if (t < 16) invs[t] = 1.f / (red[t] + red[t + 16]);
  __syncthreads();

  // PV: thread = (q, 4-dim group dg)
  int dg = t >> 4;
  float4 acc = make_float4(0.f, 0.f, 0.f, 0.f);
  const float* vb = v + (size_t)b * SEQ * DIM + h * HD + dg * 4;
#pragma unroll 4
  for (int k = 0; k < SEQ; ++k) {
    float w = wls[q][k];
    float4 vv = *(const float4*)(vb + (size_t)k * DIM);
    acc.x = fmaf(w, vv.x, acc.x);
    acc.y = fmaf(w, vv.y, acc.y);
    acc.z = fmaf(w, vv.z, acc.z);
    acc.w = fmaf(w, vv.w, acc.w);
  }
  float inv = invs[q];
  acc.x *= inv; acc.y *= inv; acc.z *= inv; acc.w *= inv;
  *(float4*)(ctx + (size_t)(b * SEQ + q0 + q) * DIM + h * HD + dg * 4) = acc;
}

extern "C" void kernel_launch(void* const* d_in, const int* in_sizes, int n_in,
                              void* d_out, int out_size, void* d_ws, size_t ws_size,
                              hipStream_t stream) {
  const float* x  = (const float*)d_in[0];
  const float* Wq = (const float*)d_in[1];
  const float* bq = (const float*)d_in[2];
  const float* Wk = (const float*)d_in[3];
  const float* bk = (const float*)d_in[4];
  const float* Wv = (const float*)d_in[5];
  const float* bv = (const float*)d_in[6];
  const float* Wo = (const float*)d_in[7];
  const float* bo = (const float*)d_in[8];

  float* ws = (float*)d_ws;
  const int M = BSZ * SEQ;             // 1024
  const size_t TOK = (size_t)M * DIM;  // 524288
  float* q   = ws;
  float* k   = q + TOK;
  float* v   = k + TOK;
  float* ctx = v + TOK;
  float* qn2 = ctx + TOK;
  float* kn2 = qn2 + (size_t)M * NH;

  dim3 gqkv(M / 64, DIM / 64, 3);
  gemm3_kernel<<<gqkv, 256, 0, stream>>>(x, Wq, Wk, Wv, bq, bk, bv, q, k, v);

  int nvec = M * NH;  // 8192
  expmap_kernel<<<nvec / 4, 256, 0, stream>>>(q, qn2, nvec);
  expmap_kernel<<<nvec / 4, 256, 0, stream>>>(k, kn2, nvec);

  dim3 ga(SEQ / 16, NH, BSZ);
  attn_kernel<<<ga, 256, 0, stream>>>(q, k, v, qn2, kn2, ctx);

  dim3 go(M / 64, DIM / 64, 1);
  gemm3_kernel<<<go, 256, 0, stream>>>(ctx, Wo, Wo, Wo, bo, bo, bo,
                                       (float*)d_out, (float*)d_out, (float*)d_out);
}

// Round 3
// 113.167 us; speedup vs baseline: 5.9609x; 1.1322x over previous
//
#include <hip/hip_runtime.h>
#include <math.h>

#define EPSF 1e-5f

constexpr int SEQ = 512;
constexpr int DIM = 512;
constexpr int BSZ = 2;
constexpr int NH  = 8;
constexpr int HD  = 64;

// ---- tiled GEMM: y = x @ W.T + b. Tile 32(M)x64(N), 256 thr, 2x4 micro,
// K-step 32. blockIdx.z selects among 3 weight/bias/out sets.
__global__ __launch_bounds__(256) void gemm3_kernel(
    const float* __restrict__ x,
    const float* __restrict__ W0, const float* __restrict__ W1, const float* __restrict__ W2,
    const float* __restrict__ b0, const float* __restrict__ b1, const float* __restrict__ b2,
    float* __restrict__ y0, float* __restrict__ y1, float* __restrict__ y2) {
  const float* W    = blockIdx.z == 0 ? W0 : (blockIdx.z == 1 ? W1 : W2);
  const float* bias = blockIdx.z == 0 ? b0 : (blockIdx.z == 1 ? b1 : b2);
  float*       y    = blockIdx.z == 0 ? y0 : (blockIdx.z == 1 ? y1 : y2);

  __shared__ float xs[32][33];
  __shared__ float ws[32][68];
  int t = threadIdx.x;
  int m0 = blockIdx.x * 32, n0 = blockIdx.y * 64;
  int tn = t & 15, tm = t >> 4;
  float acc[2][4] = {};

  for (int k0 = 0; k0 < DIM; k0 += 32) {
    __syncthreads();
    {  // stage x tile: 32 rows x 32 k = 256 float4, one per thread
      int row = t >> 3, c4 = t & 7;
      float4 xv = *(const float4*)(x + (size_t)(m0 + row) * DIM + k0 + c4 * 4);
      xs[c4 * 4 + 0][row] = xv.x; xs[c4 * 4 + 1][row] = xv.y;
      xs[c4 * 4 + 2][row] = xv.z; xs[c4 * 4 + 3][row] = xv.w;
    }
#pragma unroll
    for (int i = 0; i < 2; ++i) {  // stage w tile: 64 rows x 32 k = 512 float4
      int idx = t + i * 256;
      int wr = idx >> 3, wc = idx & 7;
      float4 wv = *(const float4*)(W + (size_t)(n0 + wr) * DIM + k0 + wc * 4);
      ws[wc * 4 + 0][wr] = wv.x; ws[wc * 4 + 1][wr] = wv.y;
      ws[wc * 4 + 2][wr] = wv.z; ws[wc * 4 + 3][wr] = wv.w;
    }
    __syncthreads();
#pragma unroll
    for (int kk = 0; kk < 32; ++kk) {
      float a0 = xs[kk][tm * 2 + 0];
      float a1 = xs[kk][tm * 2 + 1];
      float4 b4 = *(float4*)&ws[kk][tn * 4];
      acc[0][0] = fmaf(a0, b4.x, acc[0][0]); acc[0][1] = fmaf(a0, b4.y, acc[0][1]);
      acc[0][2] = fmaf(a0, b4.z, acc[0][2]); acc[0][3] = fmaf(a0, b4.w, acc[0][3]);
      acc[1][0] = fmaf(a1, b4.x, acc[1][0]); acc[1][1] = fmaf(a1, b4.y, acc[1][1]);
      acc[1][2] = fmaf(a1, b4.z, acc[1][2]); acc[1][3] = fmaf(a1, b4.w, acc[1][3]);
    }
  }
  float4 b4 = *(const float4*)(bias + n0 + tn * 4);
#pragma unroll
  for (int i = 0; i < 2; ++i) {
    float4 o = make_float4(acc[i][0] + b4.x, acc[i][1] + b4.y,
                           acc[i][2] + b4.z, acc[i][3] + b4.w);
    *(float4*)(y + (size_t)(m0 + tm * 2 + i) * DIM + n0 + tn * 4) = o;
  }
}

// exp_map_zero + project, in place. blockIdx.y: 0 -> q array, 1 -> k array.
__global__ __launch_bounds__(256) void expmap_kernel(
    float* __restrict__ tq, float* __restrict__ n2q,
    float* __restrict__ tk, float* __restrict__ n2k, int nvec) {
  float* t  = blockIdx.y == 0 ? tq  : tk;
  float* n2 = blockIdx.y == 0 ? n2q : n2k;
  int vec = blockIdx.x * 4 + (threadIdx.x >> 6);
  int lane = threadIdx.x & 63;
  if (vec >= nvec) return;
  float val = t[(size_t)vec * HD + lane];
  float ss = val * val;
#pragma unroll
  for (int m = 1; m < 64; m <<= 1) ss += __shfl_xor(ss, m);
  float r = fmaxf(sqrtf(ss), EPSF);
  float tn = fminf(tanhf(r), 0.999f);
  float mu = tn / r;
  t[(size_t)vec * HD + lane] = val * mu;
  if (lane == 0) n2[vec] = tn * tn;
}

// Block = (b, h, 16-query tile), 512 threads (8 waves).
// Dot phase: thread = (qp in 8, dh in 2, kc in 32): holds HALF (32 dims) of
// two Q rows (qp, qp+8) in registers; computes half-dots for keys 2kc,2kc+1;
// combines halves via shfl_xor(8); runs hyperbolic chain for key 2kc+dh.
// PV phase: thread = (dg in 16, khalf in 2, q in 16), float4 dims, key-halves
// combined through LDS.
__global__ __launch_bounds__(512) void attn_kernel(
    const float* __restrict__ qh, const float* __restrict__ kh,
    const float* __restrict__ v, const float* __restrict__ qn2,
    const float* __restrict__ kn2, float* __restrict__ ctx) {
  int b = blockIdx.z, h = blockIdx.y, q0 = blockIdx.x * 16;
  int t = threadIdx.x;
  __shared__ float ks[64][68];        // K chunk (64 keys x 64 dims)
  __shared__ float wls[16][524];      // exp-weights, 16 q x 512 keys
  __shared__ float partial[16][HD];   // PV khalf=1 partials
  __shared__ float red2[8][16];
  __shared__ float qn2s[16];
  __shared__ float kn2s[64];
  __shared__ float invs[16];

  int qp = t & 7;
  int dh = (t >> 3) & 1;
  int kc = t >> 4;                    // [0,32)

  // half Q rows (32 dims each) for queries qp and qp+8
  float4 qa[8], qb[8];
  {
    const float4* qra = (const float4*)(qh + (size_t)(b * SEQ + q0 + qp) * DIM + h * HD) + dh * 8;
    const float4* qrb = (const float4*)(qh + (size_t)(b * SEQ + q0 + qp + 8) * DIM + h * HD) + dh * 8;
#pragma unroll
    for (int i = 0; i < 8; ++i) { qa[i] = qra[i]; qb[i] = qrb[i]; }
  }
  if (t < 16) qn2s[t] = qn2[(size_t)(b * SEQ + q0 + t) * NH + h];
  __syncthreads();
  float qnA = qn2s[qp], qnB = qn2s[qp + 8];
  float BqA = 1.f - qnA, BqB = 1.f - qnB;
  float sumA = 0.f, sumB = 0.f;

  for (int c = 0; c < 8; ++c) {
    __syncthreads();
    {  // stage 64 keys x 64 dims = 1024 float4, 2 per thread
      int idx = t;
#pragma unroll
      for (int i = 0; i < 2; ++i, idx += 512) {
        int row = idx >> 4, c4 = idx & 15;
        float4 kv = *(const float4*)(kh + (size_t)(b * SEQ + c * 64 + row) * DIM + h * HD + c4 * 4);
        *(float4*)&ks[row][c4 * 4] = kv;
      }
    }
    if (t < 64) kn2s[t] = kn2[(size_t)(b * SEQ + c * 64 + t) * NH + h];
    __syncthreads();

    // half-dots for keys k0=2kc, k1=2kc+1 over dims [dh*32, dh*32+32)
    float hA0 = 0.f, hB0 = 0.f, hA1 = 0.f, hB1 = 0.f;
    int doff = dh * 8;  // in float4 units
#pragma unroll
    for (int d4 = 0; d4 < 8; ++d4) {
      float4 k0v = *(float4*)&ks[2 * kc + 0][(doff + d4) * 4];
      float4 k1v = *(float4*)&ks[2 * kc + 1][(doff + d4) * 4];
      float4 qav = qa[d4], qbv = qb[d4];
      hA0 = fmaf(qav.x, k0v.x, hA0); hA0 = fmaf(qav.y, k0v.y, hA0);
      hA0 = fmaf(qav.z, k0v.z, hA0); hA0 = fmaf(qav.w, k0v.w, hA0);
      hB0 = fmaf(qbv.x, k0v.x, hB0); hB0 = fmaf(qbv.y, k0v.y, hB0);
      hB0 = fmaf(qbv.z, k0v.z, hB0); hB0 = fmaf(qbv.w, k0v.w, hB0);
      hA1 = fmaf(qav.x, k1v.x, hA1); hA1 = fmaf(qav.y, k1v.y, hA1);
      hA1 = fmaf(qav.z, k1v.z, hA1); hA1 = fmaf(qav.w, k1v.w, hA1);
      hB1 = fmaf(qbv.x, k1v.x, hB1); hB1 = fmaf(qbv.y, k1v.y, hB1);
      hB1 = fmaf(qbv.z, k1v.z, hB1); hB1 = fmaf(qbv.w, k1v.w, hB1);
    }
    // combine D-halves (partner differs only in dh bit = lane bit 3)
    float fA0 = hA0 + __shfl_xor(hA0, 8);
    float fB0 = hB0 + __shfl_xor(hB0, 8);
    float fA1 = hA1 + __shfl_xor(hA1, 8);
    float fB1 = hB1 + __shfl_xor(hB1, 8);
    // this thread's key: 2kc+dh
    float dotA = dh ? fA1 : fA0;
    float dotB = dh ? fB1 : fB0;
    int key = 2 * kc + dh;
    float kn = kn2s[key];

    float A_ = 1.f - 2.f * dotA + kn;
    float den = fmaxf(1.f - 2.f * dotA + qnA * kn, EPSF);
    float num2 = fmaxf(A_ * A_ * qnA - 2.f * A_ * BqA * dotA + BqA * BqA * kn, 0.f);
    float n1 = fminf(__fsqrt_rn(num2) / den, 0.999f);
    float dist = __logf((1.f + n1) / (1.f - n1));
    float wA = __expf(fminf(fmaxf(-dist * 0.125f, -50.f), 0.f));

    A_ = 1.f - 2.f * dotB + kn;
    den = fmaxf(1.f - 2.f * dotB + qnB * kn, EPSF);
    num2 = fmaxf(A_ * A_ * qnB - 2.f * A_ * BqB * dotB + BqB * BqB * kn, 0.f);
    n1 = fminf(__fsqrt_rn(num2) / den, 0.999f);
    dist = __logf((1.f + n1) / (1.f - n1));
    float wB = __expf(fminf(fmaxf(-dist * 0.125f, -50.f), 0.f));

    sumA += wA; sumB += wB;
    wls[qp][c * 64 + key] = wA;
    wls[qp + 8][c * 64 + key] = wB;
  }

  // reduce weight sums over lane bits 3,4,5 (dh + in-wave kc), then waves
#pragma unroll
  for (int m = 8; m < 64; m <<= 1) {
    sumA += __shfl_xor(sumA, m);
    sumB += __shfl_xor(sumB, m);
  }
  int lane = t & 63, wv = t >> 6;
  if (lane < 8) { red2[wv][lane] = sumA; red2[wv][lane + 8] = sumB; }
  __syncthreads();
  if (t < 16) {
    float s = 0.f;
#pragma unroll
    for (int w = 0; w < 8; ++w) s += red2[w][t];
    invs[t] = 1.f / s;
  }
  __syncthreads();

  // PV: thread = (dg, khalf, q)
  int dg = t & 15, khf = (t >> 4) & 1, qq = t >> 5;
  const float* vb = v + (size_t)b * SEQ * DIM + h * HD + dg * 4;
  int kbase = khf * 256;
  float4 acc = make_float4(0.f, 0.f, 0.f, 0.f);
  for (int k4 = 0; k4 < 64; ++k4) {
    float4 w4 = *(float4*)&wls[qq][kbase + k4 * 4];
    const float* vk = vb + (size_t)(kbase + k4 * 4) * DIM;
    float4 v0 = *(const float4*)(vk);
    float4 v1 = *(const float4*)(vk + DIM);
    float4 v2 = *(const float4*)(vk + 2 * DIM);
    float4 v3 = *(const float4*)(vk + 3 * DIM);
    acc.x = fmaf(w4.x, v0.x, acc.x); acc.y = fmaf(w4.x, v0.y, acc.y);
    acc.z = fmaf(w4.x, v0.z, acc.z); acc.w = fmaf(w4.x, v0.w, acc.w);
    acc.x = fmaf(w4.y, v1.x, acc.x); acc.y = fmaf(w4.y, v1.y, acc.y);
    acc.z = fmaf(w4.y, v1.z, acc.z); acc.w = fmaf(w4.y, v1.w, acc.w);
    acc.x = fmaf(w4.z, v2.x, acc.x); acc.y = fmaf(w4.z, v2.y, acc.y);
    acc.z = fmaf(w4.z, v2.z, acc.z); acc.w = fmaf(w4.z, v2.w, acc.w);
    acc.x = fmaf(w4.w, v3.x, acc.x); acc.y = fmaf(w4.w, v3.y, acc.y);
    acc.z = fmaf(w4.w, v3.z, acc.z); acc.w = fmaf(w4.w, v3.w, acc.w);
  }
  if (khf == 1) *(float4*)&partial[qq][dg * 4] = acc;
  __syncthreads();
  if (khf == 0) {
    float4 p = *(float4*)&partial[qq][dg * 4];
    float inv = invs[qq];
    acc.x = (acc.x + p.x) * inv; acc.y = (acc.y + p.y) * inv;
    acc.z = (acc.z + p.z) * inv; acc.w = (acc.w + p.w) * inv;
    *(float4*)(ctx + (size_t)(b * SEQ + q0 + qq) * DIM + h * HD + dg * 4) = acc;
  }
}

extern "C" void kernel_launch(void* const* d_in, const int* in_sizes, int n_in,
                              void* d_out, int out_size, void* d_ws, size_t ws_size,
                              hipStream_t stream) {
  const float* x  = (const float*)d_in[0];
  const float* Wq = (const float*)d_in[1];
  const float* bq = (const float*)d_in[2];
  const float* Wk = (const float*)d_in[3];
  const float* bk = (const float*)d_in[4];
  const float* Wv = (const float*)d_in[5];
  const float* bv = (const float*)d_in[6];
  const float* Wo = (const float*)d_in[7];
  const float* bo = (const float*)d_in[8];

  float* ws = (float*)d_ws;
  const int M = BSZ * SEQ;             // 1024
  const size_t TOK = (size_t)M * DIM;  // 524288
  float* q   = ws;
  float* k   = q + TOK;
  float* v   = k + TOK;
  float* ctx = v + TOK;
  float* qn2 = ctx + TOK;
  float* kn2 = qn2 + (size_t)M * NH;

  dim3 gqkv(M / 32, DIM / 64, 3);
  gemm3_kernel<<<gqkv, 256, 0, stream>>>(x, Wq, Wk, Wv, bq, bk, bv, q, k, v);

  int nvec = M * NH;  // 8192
  dim3 ge(nvec / 4, 2);
  expmap_kernel<<<ge, 256, 0, stream>>>(q, qn2, k, kn2, nvec);

  dim3 ga(SEQ / 16, NH, BSZ);
  attn_kernel<<<ga, 512, 0, stream>>>(q, k, v, qn2, kn2, ctx);

  dim3 go(M / 32, DIM / 64, 1);
  gemm3_kernel<<<go, 256, 0, stream>>>(ctx, Wo, Wo, Wo, bo, bo, bo,
                                       (float*)d_out, (float*)d_out, (float*)d_out);
}